// Round 3
// baseline (125.854 us; speedup 1.0000x reference)
//
#include <hip/hip_runtime.h>
#include <cstdint>
#include <cstddef>

// Problem constants (B=8, H=W=1024)
#define N_PIX   1048576
#define B_ROWS  8
#define K_ALL   524288          // max(1, int(N*0.5))
#define WG_PER_ROW 256          // pass1 blocks per row
#define ITERS   4               // quads per thread: (N_PIX/4)/WG_PER_ROW/256
#define NBINS   1024            // linear bins, width 1/128 on [0,8)
#define FXSHIFT 11              // bin = fx >> 11 (2^18 fixed-point -> 128 bins/unit)
#define CSHIFT  42              // u64 = (count << 42) | fixed_sum(2^-18)
#define SUMMASK ((1ull << CSHIFT) - 1ull)
#define FPSCALE 262144.0f       // 2^18 fixed-point scale for packed sums

// R2 post-mortem: linear binning was NEUTRAL (bank conflicts halved, time flat)
// -> LDS atomics were not the bottleneck. pass1 counters showed VGPR=28:
// the scheduler sank the 12-load prefetch into per-iteration load->wait->proc,
// leaving ~1 load in flight per wave (VALU 18%, HBM 17%, 80% stall).
// Fix here: sched_barrier(0) pins all 12 loads before any compute; no
// min-occupancy launch_bounds so regalloc can keep 48+ data VGPRs live.
// LDS init runs after load-issue (overlaps latency).
//
// Packing margins: per-row bin count <= ~0.25M < 2^22 (CSHIFT=42 leaves 22);
// per-row bin fixed sum <= 0.25M * 8 * 2^18 = 5.2e11 < 2^42. Per-block far less.
// R1 lesson: no single-kernel fusion -- __threadfence() on gfx950 is a full
// L2 writeback/invalidate per block (8x slowdown). Two dispatches stay.

// ---------- K1: loss + packed count/sum LDS hist + per-block npos/sumPos ----------
__global__ __launch_bounds__(256) void k_pass1(
    const float4* __restrict__ lg, const int4* __restrict__ tg, const int4* __restrict__ mk,
    unsigned long long* __restrict__ hist,
    unsigned* __restrict__ partNpos, double* __restrict__ partSpos, float* __restrict__ out)
{
    __shared__ unsigned long long hq[NBINS];   // 8 KB
    __shared__ unsigned swp[4];
    __shared__ double   sws[4];
    const int tid = threadIdx.x;

    const int r = blockIdx.x >> 8;                          // WG_PER_ROW == 256
    const size_t base = (size_t)blockIdx.x * (ITERS * 256) + tid;

    // Issue ALL 12 16B loads back-to-back; sched_barrier(0) forbids the
    // scheduler from sinking any of them below this point (keeps 12 in flight).
    float4 x[ITERS]; int4 t[ITERS]; int4 m[ITERS];
    #pragma unroll
    for (int i = 0; i < ITERS; ++i) {
        x[i] = lg[base + (size_t)i * 256];
        t[i] = tg[base + (size_t)i * 256];
        m[i] = mk[base + (size_t)i * 256];
    }
    __builtin_amdgcn_sched_barrier(0);

    // LDS init overlaps the load latency
    for (int b = tid; b < NBINS; b += 256) hq[b] = 0ull;
    if (blockIdx.x == 0 && tid == 0) *out = 0.f;   // k_final (later dispatch) accumulates
    __syncthreads();   // LDS init visible before any atomics

    unsigned npos = 0; float spos = 0.f;

    auto proc = [&](float xx, int tt, int mm) {
        float ax = fabsf(xx);
        float e = __expf(-ax);
        float l = __logf(1.f + e);
        float bce = fmaxf(xx, 0.f) - xx * (float)tt + l;
        if (mm) {
            if (tt) { npos++; spos += bce; }
            else {
                unsigned fx = (unsigned)__float2uint_rn(bce * FPSCALE);
                unsigned bin = fx >> FXSHIFT;
                if (bin >= NBINS) bin = NBINS - 1;          // tail guard (bce<8 in data)
                atomicAdd(&hq[bin], (1ull << CSHIFT) | (unsigned long long)fx);
            }
        }
    };

    #pragma unroll
    for (int i = 0; i < ITERS; ++i) {
        proc(x[i].x, t[i].x, m[i].x);
        proc(x[i].y, t[i].y, m[i].y);
        proc(x[i].z, t[i].z, m[i].z);
        proc(x[i].w, t[i].w, m[i].w);
    }

    // block-level reduce of npos/sumPos -> per-block partials
    for (int o = 32; o; o >>= 1) {
        npos += __shfl_down(npos, o);
        spos += __shfl_down(spos, o);
    }
    if ((tid & 63) == 0) { swp[tid >> 6] = npos; sws[tid >> 6] = (double)spos; }
    __syncthreads();
    if (tid == 0) {
        partNpos[blockIdx.x] = swp[0] + swp[1] + swp[2] + swp[3];
        partSpos[blockIdx.x] = sws[0] + sws[1] + sws[2] + sws[3];
    }

    // flush nonzero bins -> global row hist (one u64 atomic per occupied bin)
    unsigned long long* gh = hist + (size_t)r * NBINS;
    for (int b = tid; b < NBINS; b += 256) {
        unsigned long long v = hq[b];
        if (v) atomicAdd(&gh[b], v);
    }
}

// ---------- K2: per-row selection from packed hist + output ----------
__global__ __launch_bounds__(256) void k_final(
    const unsigned long long* __restrict__ hist,
    const unsigned* __restrict__ partNpos, const double* __restrict__ partSpos,
    float* __restrict__ out)
{
    __shared__ unsigned sc[2][256];
    __shared__ double   sd[2][256];
    __shared__ unsigned swp[4];
    __shared__ double   sws[4];
    __shared__ int rT; __shared__ unsigned rcntgt; __shared__ double rsumgt;

    const int r = blockIdx.x, tid = threadIdx.x;
    const unsigned long long* gh = hist + (size_t)r * NBINS;
    const double inv = 1.0 / (double)FPSCALE;

    // reduce per-block partials (WG_PER_ROW == 256 entries)
    {
        unsigned np = partNpos[r * 256 + tid];
        double   sp = partSpos[r * 256 + tid];
        for (int o = 32; o; o >>= 1) { np += __shfl_down(np, o); sp += __shfl_down(sp, o); }
        if ((tid & 63) == 0) { swp[tid >> 6] = np; sws[tid >> 6] = sp; }
    }
    __syncthreads();
    const unsigned npos = swp[0] + swp[1] + swp[2] + swp[3];
    const double sumPos = sws[0] + sws[1] + sws[2] + sws[3];
    __syncthreads();

    // per-thread chunk of 4 bins, scanned high->low; cache unpacked values
    const int per = NBINS / 256;                 // 4
    const int b0 = NBINS - 1 - tid * per;
    unsigned lc[4]; double lsum[4];
    unsigned pc = 0; double ps = 0.0;
    #pragma unroll
    for (int i = 0; i < per; ++i) {
        unsigned long long v = gh[b0 - i];
        lc[i] = (unsigned)(v >> CSHIFT);
        lsum[i] = (double)(v & SUMMASK) * inv;
        pc += lc[i]; ps += lsum[i];
    }

    // inclusive Hillis-Steele scan (thread t covers bins >= NBINS - per*(t+1))
    int pp = 0;
    sc[0][tid] = pc; sd[0][tid] = ps;
    __syncthreads();
    for (int ofs = 1; ofs < 256; ofs <<= 1) {
        unsigned c = sc[pp][tid]; double s = sd[pp][tid];
        if (tid >= ofs) { c += sc[pp][tid - ofs]; s += sd[pp][tid - ofs]; }
        sc[pp ^ 1][tid] = c; sd[pp ^ 1][tid] = s;
        pp ^= 1;
        __syncthreads();
    }
    const unsigned nneg   = sc[pp][255];
    const double   sumNeg = sd[pp][255];

    long kl = (long)K_ALL - (long)npos;
    if (kl < 0) kl = 0;
    if (kl > (long)nneg) kl = (long)nneg;
    const unsigned Kneg = (unsigned)kl;

    double sum_sel = 0.0;
    if (Kneg >= nneg) {
        sum_sel = sumNeg;                        // keep-all (or Kneg==nneg==0)
    } else if (Kneg > 0) {
        // threshold bin: exactly one thread has exc < Kneg <= inc
        unsigned inc = sc[pp][tid];
        unsigned exc = inc - pc;
        double   exs = sd[pp][tid] - ps;
        if (exc < Kneg && Kneg <= inc) {
            unsigned cum = exc; double csum = exs;
            #pragma unroll
            for (int i = 0; i < per; ++i) {
                if (cum + lc[i] >= Kneg) { rT = b0 - i; rcntgt = cum; rsumgt = csum; break; }
                cum += lc[i]; csum += lsum[i];
            }
        }
        __syncthreads();
        if (tid == 0) {
            const int T1 = rT;
            unsigned long long v = gh[T1];
            const unsigned cntT1 = (unsigned)(v >> CSHIFT);
            const double   sumT1 = (double)(v & SUMMASK) * inv;
            const unsigned Kp = Kneg - rcntgt;   // 1..cntT1
            const double lo = (double)T1 * (1.0 / 128.0);
            const double hi = (double)(T1 + 1) * (1.0 / 128.0);
            const double w = hi - lo;            // 1/128
            const double avg = sumT1 / (double)cntT1;
            // shifted-uniform top-Kp mean; exact when Kp == cntT1
            const double topmean = avg + 0.5 * w * (1.0 - (double)Kp / (double)cntT1);
            sum_sel = rsumgt + (double)Kp * topmean;
        }
    }

    if (tid == 0) {
        unsigned long long kk = (unsigned long long)npos + (unsigned long long)Kneg;
        double per_s = 0.0;
        if (kk > 0) per_s = (sumPos + sum_sel) / (double)kk;
        // kk==0 => no tissue => reference falls back to loss[:,0] == 0
        atomicAdd(out, (float)(per_s / (double)B_ROWS));
    }
}

// ---------- launch ----------
extern "C" void kernel_launch(void* const* d_in, const int* in_sizes, int n_in,
                              void* d_out, int out_size, void* d_ws, size_t ws_size,
                              hipStream_t stream)
{
    const float* logits = (const float*)d_in[0];
    const int*   targets = (const int*)d_in[1];
    const int*   tissue = (const int*)d_in[2];

    const int NBLK = B_ROWS * WG_PER_ROW;   // 2048
    char* ws = (char*)d_ws;
    size_t off = 0;
    // zeroed region: packed hist (at ws start)
    unsigned long long* hist = (unsigned long long*)(ws + off);
    off += (size_t)B_ROWS * NBINS * 8;      // 64 KB
    size_t zero_size = off;
    // non-zeroed partials (every slot written before read)
    unsigned* partNpos = (unsigned*)(ws + off); off += (size_t)NBLK * 4;
    double*   partSpos = (double*)(ws + off);   off += (size_t)NBLK * 8;

    hipMemsetAsync(ws, 0, zero_size, stream);

    k_pass1<<<NBLK, 256, 0, stream>>>(
        (const float4*)logits, (const int4*)targets, (const int4*)tissue,
        hist, partNpos, partSpos, (float*)d_out);
    k_final<<<B_ROWS, 256, 0, stream>>>(hist, partNpos, partSpos, (float*)d_out);
}

// Round 4
// 123.528 us; speedup vs baseline: 1.0188x; 1.0188x over previous
//
#include <hip/hip_runtime.h>
#include <cstdint>
#include <cstddef>

// Problem constants (B=8, H=W=1024)
#define N_PIX   1048576
#define B_ROWS  8
#define K_ALL   524288          // max(1, int(N*0.5))
#define WG_PER_ROW 256          // pass1 blocks per row
#define ITERS   4               // quads per thread: (N_PIX/4)/WG_PER_ROW/256
#define NBINS   1024            // linear bins, width 1/128 on [0,8)
#define FXSHIFT 11              // bin = fx >> 11 (2^18 fixed-point -> 128 bins/unit)
#define NCOPY   8               // hist copies (XCD-private under round-robin dispatch)
#define CSHIFT  42              // u64 = (count << 42) | fixed_sum(2^-18)
#define SUMMASK ((1ull << CSHIFT) - 1ull)
#define FPSCALE 262144.0f       // 2^18 fixed-point scale for packed sums

// R3 post-mortem: ALL prior pass1 variants had __syncthreads() between
// load-issue and compute. hipcc emits s_waitcnt vmcnt(0) before s_barrier
// (measured, guide §5) -> the 12-load prefetch was fully drained at the
// barrier every round; zero load/compute overlap (VALU 18%, HBM 17%).
// Fix: LDS init + barrier FIRST (drains only lgkmcnt), then issue loads,
// fenced by sched_barrier(0) on both sides so they neither hoist above the
// barrier nor sink into the loop.
// Also: flush was ~1M device u64 atomics from 2048 blocks bursting into one
// 64KB hist shared by 8 XCDs (line ping-pong). Now NCOPY=8 copies indexed by
// blockIdx.x&7 -> XCD-private under round-robin dispatch; k_final sums copies.
// Packing margins with full-row worst case: count <= 262K < 2^22; fixed sum
// <= 262K * 2^21 = 5.5e11 < 2^42.
// R1 lesson stands: no single-kernel fusion (threadfence = L2 writeback storm).

// ---------- K1: loss + packed count/sum LDS hist + per-block npos/sumPos ----------
__global__ __launch_bounds__(256) void k_pass1(
    const float4* __restrict__ lg, const int4* __restrict__ tg, const int4* __restrict__ mk,
    unsigned long long* __restrict__ hist,
    unsigned* __restrict__ partNpos, double* __restrict__ partSpos, float* __restrict__ out)
{
    __shared__ unsigned long long hq[NBINS];   // 8 KB
    __shared__ unsigned swp[4];
    __shared__ double   sws[4];
    const int tid = threadIdx.x;

    // LDS init FIRST; this barrier drains only the ds_writes (cheap)
    for (int b = tid; b < NBINS; b += 256) hq[b] = 0ull;
    if (blockIdx.x == 0 && tid == 0) *out = 0.f;   // k_final (later dispatch) accumulates
    __syncthreads();
    __builtin_amdgcn_sched_barrier(0);   // don't let loads hoist above the barrier

    const int r = blockIdx.x >> 8;                          // WG_PER_ROW == 256
    const size_t base = (size_t)blockIdx.x * (ITERS * 256) + tid;

    // Issue ALL 12 16B loads back-to-back; nothing between them and compute
    // forces a drain -- compiler inserts fine-grained vmcnt(N) per quad.
    float4 x[ITERS]; int4 t[ITERS]; int4 m[ITERS];
    #pragma unroll
    for (int i = 0; i < ITERS; ++i) {
        x[i] = lg[base + (size_t)i * 256];
        t[i] = tg[base + (size_t)i * 256];
        m[i] = mk[base + (size_t)i * 256];
    }
    __builtin_amdgcn_sched_barrier(0);   // don't let loads sink into the loop

    unsigned npos = 0; float spos = 0.f;

    auto proc = [&](float xx, int tt, int mm) {
        float ax = fabsf(xx);
        float e = __expf(-ax);
        float l = __logf(1.f + e);
        float bce = fmaxf(xx, 0.f) - xx * (float)tt + l;
        if (mm) {
            if (tt) { npos++; spos += bce; }
            else {
                unsigned fx = (unsigned)__float2uint_rn(bce * FPSCALE);
                unsigned bin = fx >> FXSHIFT;
                if (bin >= NBINS) bin = NBINS - 1;          // tail guard (bce<8 in data)
                atomicAdd(&hq[bin], (1ull << CSHIFT) | (unsigned long long)fx);
            }
        }
    };

    #pragma unroll
    for (int i = 0; i < ITERS; ++i) {
        proc(x[i].x, t[i].x, m[i].x);
        proc(x[i].y, t[i].y, m[i].y);
        proc(x[i].z, t[i].z, m[i].z);
        proc(x[i].w, t[i].w, m[i].w);
    }

    // block-level reduce of npos/sumPos -> per-block partials
    for (int o = 32; o; o >>= 1) {
        npos += __shfl_down(npos, o);
        spos += __shfl_down(spos, o);
    }
    if ((tid & 63) == 0) { swp[tid >> 6] = npos; sws[tid >> 6] = (double)spos; }
    __syncthreads();   // also makes hq atomics visible for the flush
    if (tid == 0) {
        partNpos[blockIdx.x] = swp[0] + swp[1] + swp[2] + swp[3];
        partSpos[blockIdx.x] = sws[0] + sws[1] + sws[2] + sws[3];
    }

    // flush nonzero bins -> XCD-private hist copy (one u64 atomic per bin)
    unsigned long long* gh = hist + ((size_t)r * NCOPY + (blockIdx.x & (NCOPY - 1))) * NBINS;
    for (int b = tid; b < NBINS; b += 256) {
        unsigned long long v = hq[b];
        if (v) atomicAdd(&gh[b], v);
    }
}

// ---------- K2: per-row selection from packed hist + output ----------
__global__ __launch_bounds__(256) void k_final(
    const unsigned long long* __restrict__ hist,
    const unsigned* __restrict__ partNpos, const double* __restrict__ partSpos,
    float* __restrict__ out)
{
    __shared__ unsigned sc[2][256];
    __shared__ double   sd[2][256];
    __shared__ unsigned swp[4];
    __shared__ double   sws[4];
    __shared__ int rT; __shared__ unsigned rcntgt, rcnt1;
    __shared__ double rsumgt, rsum1;

    const int r = blockIdx.x, tid = threadIdx.x;
    const unsigned long long* gh = hist + (size_t)r * NCOPY * NBINS;
    const double inv = 1.0 / (double)FPSCALE;

    // reduce per-block partials (WG_PER_ROW == 256 entries)
    {
        unsigned np = partNpos[r * 256 + tid];
        double   sp = partSpos[r * 256 + tid];
        for (int o = 32; o; o >>= 1) { np += __shfl_down(np, o); sp += __shfl_down(sp, o); }
        if ((tid & 63) == 0) { swp[tid >> 6] = np; sws[tid >> 6] = sp; }
    }
    __syncthreads();
    const unsigned npos = swp[0] + swp[1] + swp[2] + swp[3];
    const double sumPos = sws[0] + sws[1] + sws[2] + sws[3];
    __syncthreads();

    // per-thread chunk of 4 bins (summed over the 8 copies), scanned high->low
    const int per = NBINS / 256;                 // 4
    const int b0 = NBINS - 1 - tid * per;
    unsigned lc[4]; double lsum[4];
    unsigned pc = 0; double ps = 0.0;
    #pragma unroll
    for (int i = 0; i < per; ++i) {
        unsigned long long v = 0ull;
        #pragma unroll
        for (int c = 0; c < NCOPY; ++c) v += gh[(size_t)c * NBINS + (b0 - i)];
        lc[i] = (unsigned)(v >> CSHIFT);
        lsum[i] = (double)(v & SUMMASK) * inv;
        pc += lc[i]; ps += lsum[i];
    }

    // inclusive Hillis-Steele scan (thread t covers bins >= NBINS - per*(t+1))
    int pp = 0;
    sc[0][tid] = pc; sd[0][tid] = ps;
    __syncthreads();
    for (int ofs = 1; ofs < 256; ofs <<= 1) {
        unsigned c = sc[pp][tid]; double s = sd[pp][tid];
        if (tid >= ofs) { c += sc[pp][tid - ofs]; s += sd[pp][tid - ofs]; }
        sc[pp ^ 1][tid] = c; sd[pp ^ 1][tid] = s;
        pp ^= 1;
        __syncthreads();
    }
    const unsigned nneg   = sc[pp][255];
    const double   sumNeg = sd[pp][255];

    long kl = (long)K_ALL - (long)npos;
    if (kl < 0) kl = 0;
    if (kl > (long)nneg) kl = (long)nneg;
    const unsigned Kneg = (unsigned)kl;

    double sum_sel = 0.0;
    if (Kneg >= nneg) {
        sum_sel = sumNeg;                        // keep-all (or Kneg==nneg==0)
    } else if (Kneg > 0) {
        // threshold bin: exactly one thread has exc < Kneg <= inc
        unsigned inc = sc[pp][tid];
        unsigned exc = inc - pc;
        double   exs = sd[pp][tid] - ps;
        if (exc < Kneg && Kneg <= inc) {
            unsigned cum = exc; double csum = exs;
            #pragma unroll
            for (int i = 0; i < per; ++i) {
                if (cum + lc[i] >= Kneg) {
                    rT = b0 - i; rcntgt = cum; rsumgt = csum;
                    rcnt1 = lc[i]; rsum1 = lsum[i];        // stash: no re-read needed
                    break;
                }
                cum += lc[i]; csum += lsum[i];
            }
        }
        __syncthreads();
        if (tid == 0) {
            const int T1 = rT;
            const unsigned cntT1 = rcnt1;
            const double   sumT1 = rsum1;
            const unsigned Kp = Kneg - rcntgt;   // 1..cntT1
            const double w = 1.0 / 128.0;        // bin width
            const double avg = sumT1 / (double)cntT1;
            // shifted-uniform top-Kp mean; exact when Kp == cntT1
            const double topmean = avg + 0.5 * w * (1.0 - (double)Kp / (double)cntT1);
            sum_sel = rsumgt + (double)Kp * topmean;
            (void)T1;
        }
    }

    if (tid == 0) {
        unsigned long long kk = (unsigned long long)npos + (unsigned long long)Kneg;
        double per_s = 0.0;
        if (kk > 0) per_s = (sumPos + sum_sel) / (double)kk;
        // kk==0 => no tissue => reference falls back to loss[:,0] == 0
        atomicAdd(out, (float)(per_s / (double)B_ROWS));
    }
}

// ---------- launch ----------
extern "C" void kernel_launch(void* const* d_in, const int* in_sizes, int n_in,
                              void* d_out, int out_size, void* d_ws, size_t ws_size,
                              hipStream_t stream)
{
    const float* logits = (const float*)d_in[0];
    const int*   targets = (const int*)d_in[1];
    const int*   tissue = (const int*)d_in[2];

    const int NBLK = B_ROWS * WG_PER_ROW;   // 2048
    char* ws = (char*)d_ws;
    size_t off = 0;
    // zeroed region: packed hist copies (at ws start)
    unsigned long long* hist = (unsigned long long*)(ws + off);
    off += (size_t)B_ROWS * NCOPY * NBINS * 8;   // 512 KB
    size_t zero_size = off;
    // non-zeroed partials (every slot written before read)
    unsigned* partNpos = (unsigned*)(ws + off); off += (size_t)NBLK * 4;
    double*   partSpos = (double*)(ws + off);   off += (size_t)NBLK * 8;

    hipMemsetAsync(ws, 0, zero_size, stream);

    k_pass1<<<NBLK, 256, 0, stream>>>(
        (const float4*)logits, (const int4*)targets, (const int4*)tissue,
        hist, partNpos, partSpos, (float*)d_out);
    k_final<<<B_ROWS, 256, 0, stream>>>(hist, partNpos, partSpos, (float*)d_out);
}

// Round 5
// 121.202 us; speedup vs baseline: 1.0384x; 1.0192x over previous
//
#include <hip/hip_runtime.h>
#include <cstdint>
#include <cstddef>

// Problem constants (B=8, H=W=1024)
#define N_PIX   1048576
#define B_ROWS  8
#define K_ALL   524288          // max(1, int(N*0.5))
#define BLOCKS_PER_ROW 128      // pass1 blocks per row (1024 total, 4/CU persistent)
#define NSTAGE  8               // quads per thread, software-pipelined
#define NBINS   1024            // linear bins, width 1/128 on [0,8)
#define FXSHIFT 11              // bin = fx >> 11 (2^18 fixed-point -> 128 bins/unit)
#define NCOPY   8               // hist copies (XCD-private under round-robin dispatch)
#define CSHIFT  42              // u64 = (count << 42) | fixed_sum(2^-18)
#define SUMMASK ((1ull << CSHIFT) - 1ull)
#define FPSCALE 262144.0f       // 2^18 fixed-point scale for packed sums

// R4 post-mortem: four pass1 variants (bit-bins / linear bins / pinned loads /
// barrier-before-loads) ALL land at ~40us. Common shape: single-generation
// 2048-block grid, one 12-load burst per wave, no pipeline, 1.2M-atomic flush
// burst at the end. R5 = persistent pipelined shape (one lever):
//   1024 blocks (4/CU, 16 waves/CU), 8 stages/thread, depth-1 reg pipeline:
//   issue stage j+1 loads -> sched_barrier(0) -> process stage j.
//   Steady state 3-6 loads in flight/wave * 16 waves/CU >> Little's-law need.
// If this is ALSO flat, latency/turnover is exonerated -> LDS u64 atomic base
// throughput becomes prime suspect (R2 already ruled out bank conflicts).
// Packing margins: block bin count <= 8192 < 2^22; per-(row,copy) count
// <= 131072 < 2^22, sum <= 2.7e11 < 2^42; row totals 1.05M < 2^22, 2.2e12 < 2^42.
// R1 lesson stands: no single-kernel fusion (threadfence = L2 writeback storm).

// ---------- K1: loss + packed count/sum LDS hist + per-block npos/sumPos ----------
__global__ __launch_bounds__(256) void k_pass1(
    const float4* __restrict__ lg, const int4* __restrict__ tg, const int4* __restrict__ mk,
    unsigned long long* __restrict__ hist,
    unsigned* __restrict__ partNpos, double* __restrict__ partSpos, float* __restrict__ out)
{
    __shared__ unsigned long long hq[NBINS];   // 8 KB
    __shared__ unsigned swp[4];
    __shared__ double   sws[4];
    const int tid = threadIdx.x;

    // LDS init FIRST; this barrier drains only ds_writes (cheap)
    for (int b = tid; b < NBINS; b += 256) hq[b] = 0ull;
    if (blockIdx.x == 0 && tid == 0) *out = 0.f;   // k_final (later dispatch) accumulates
    __syncthreads();
    __builtin_amdgcn_sched_barrier(0);   // loads must not hoist above the barrier

    const int r = blockIdx.x >> 7;                          // BLOCKS_PER_ROW == 128
    const size_t qbase = (size_t)blockIdx.x * (NSTAGE * 256) + tid;

    unsigned npos = 0; float spos = 0.f;

    auto proc = [&](float xx, int tt, int mm) {
        float ax = fabsf(xx);
        float e = __expf(-ax);
        float l = __logf(1.f + e);
        float bce = fmaxf(xx, 0.f) - xx * (float)tt + l;
        if (mm) {
            if (tt) { npos++; spos += bce; }
            else {
                unsigned fx = (unsigned)__float2uint_rn(bce * FPSCALE);
                unsigned bin = fx >> FXSHIFT;
                if (bin >= NBINS) bin = NBINS - 1;          // tail guard (bce<8 in data)
                atomicAdd(&hq[bin], (1ull << CSHIFT) | (unsigned long long)fx);
            }
        }
    };

    // depth-1 software pipeline over NSTAGE stages; x/t/m indexed only by
    // compile-time constants (full unroll) -> stays in registers (rule #20)
    float4 x[2]; int4 t[2]; int4 m[2];
    x[0] = lg[qbase]; t[0] = tg[qbase]; m[0] = mk[qbase];
    #pragma unroll
    for (int j = 0; j < NSTAGE; ++j) {
        const int cur = j & 1, nxt = cur ^ 1;
        if (j < NSTAGE - 1) {
            const size_t q = qbase + (size_t)(j + 1) * 256;
            x[nxt] = lg[q]; t[nxt] = tg[q]; m[nxt] = mk[q];
        }
        __builtin_amdgcn_sched_barrier(0);   // loads stay above, compute below
        proc(x[cur].x, t[cur].x, m[cur].x);
        proc(x[cur].y, t[cur].y, m[cur].y);
        proc(x[cur].z, t[cur].z, m[cur].z);
        proc(x[cur].w, t[cur].w, m[cur].w);
        __builtin_amdgcn_sched_barrier(0);   // keep stages separated
    }

    // block-level reduce of npos/sumPos -> per-block partials
    for (int o = 32; o; o >>= 1) {
        npos += __shfl_down(npos, o);
        spos += __shfl_down(spos, o);
    }
    if ((tid & 63) == 0) { swp[tid >> 6] = npos; sws[tid >> 6] = (double)spos; }
    __syncthreads();   // also makes hq atomics visible for the flush
    if (tid == 0) {
        partNpos[blockIdx.x] = swp[0] + swp[1] + swp[2] + swp[3];
        partSpos[blockIdx.x] = sws[0] + sws[1] + sws[2] + sws[3];
    }

    // flush nonzero bins -> XCD-private hist copy (one u64 atomic per occupied bin)
    unsigned long long* gh = hist + ((size_t)r * NCOPY + (blockIdx.x & (NCOPY - 1))) * NBINS;
    for (int b = tid; b < NBINS; b += 256) {
        unsigned long long v = hq[b];
        if (v) atomicAdd(&gh[b], v);
    }
}

// ---------- K2: per-row selection from packed hist + output ----------
__global__ __launch_bounds__(256) void k_final(
    const unsigned long long* __restrict__ hist,
    const unsigned* __restrict__ partNpos, const double* __restrict__ partSpos,
    float* __restrict__ out)
{
    __shared__ unsigned sc[2][256];
    __shared__ double   sd[2][256];
    __shared__ unsigned swp[4];
    __shared__ double   sws[4];
    __shared__ unsigned rcntgt, rcnt1;
    __shared__ double rsumgt, rsum1;

    const int r = blockIdx.x, tid = threadIdx.x;
    const unsigned long long* gh = hist + (size_t)r * NCOPY * NBINS;
    const double inv = 1.0 / (double)FPSCALE;

    // reduce per-block partials (BLOCKS_PER_ROW == 128 entries)
    {
        unsigned np = (tid < BLOCKS_PER_ROW) ? partNpos[r * BLOCKS_PER_ROW + tid] : 0u;
        double   sp = (tid < BLOCKS_PER_ROW) ? partSpos[r * BLOCKS_PER_ROW + tid] : 0.0;
        for (int o = 32; o; o >>= 1) { np += __shfl_down(np, o); sp += __shfl_down(sp, o); }
        if ((tid & 63) == 0) { swp[tid >> 6] = np; sws[tid >> 6] = sp; }
    }
    __syncthreads();
    const unsigned npos = swp[0] + swp[1] + swp[2] + swp[3];
    const double sumPos = sws[0] + sws[1] + sws[2] + sws[3];
    __syncthreads();

    // per-thread chunk of 4 bins (summed over the 8 copies), scanned high->low
    const int per = NBINS / 256;                 // 4
    const int b0 = NBINS - 1 - tid * per;
    unsigned lc[4]; double lsum[4];
    unsigned pc = 0; double ps = 0.0;
    #pragma unroll
    for (int i = 0; i < per; ++i) {
        unsigned long long v = 0ull;
        #pragma unroll
        for (int c = 0; c < NCOPY; ++c) v += gh[(size_t)c * NBINS + (b0 - i)];
        lc[i] = (unsigned)(v >> CSHIFT);
        lsum[i] = (double)(v & SUMMASK) * inv;
        pc += lc[i]; ps += lsum[i];
    }

    // inclusive Hillis-Steele scan (thread t covers bins >= NBINS - per*(t+1))
    int pp = 0;
    sc[0][tid] = pc; sd[0][tid] = ps;
    __syncthreads();
    for (int ofs = 1; ofs < 256; ofs <<= 1) {
        unsigned c = sc[pp][tid]; double s = sd[pp][tid];
        if (tid >= ofs) { c += sc[pp][tid - ofs]; s += sd[pp][tid - ofs]; }
        sc[pp ^ 1][tid] = c; sd[pp ^ 1][tid] = s;
        pp ^= 1;
        __syncthreads();
    }
    const unsigned nneg   = sc[pp][255];
    const double   sumNeg = sd[pp][255];

    long kl = (long)K_ALL - (long)npos;
    if (kl < 0) kl = 0;
    if (kl > (long)nneg) kl = (long)nneg;
    const unsigned Kneg = (unsigned)kl;

    double sum_sel = 0.0;
    if (Kneg >= nneg) {
        sum_sel = sumNeg;                        // keep-all (or Kneg==nneg==0)
    } else if (Kneg > 0) {
        // threshold bin: exactly one thread has exc < Kneg <= inc
        unsigned inc = sc[pp][tid];
        unsigned exc = inc - pc;
        double   exs = sd[pp][tid] - ps;
        if (exc < Kneg && Kneg <= inc) {
            unsigned cum = exc; double csum = exs;
            #pragma unroll
            for (int i = 0; i < per; ++i) {
                if (cum + lc[i] >= Kneg) {
                    rcntgt = cum; rsumgt = csum;
                    rcnt1 = lc[i]; rsum1 = lsum[i];        // stash: no re-read needed
                    break;
                }
                cum += lc[i]; csum += lsum[i];
            }
        }
        __syncthreads();
        if (tid == 0) {
            const unsigned cntT1 = rcnt1;
            const double   sumT1 = rsum1;
            const unsigned Kp = Kneg - rcntgt;   // 1..cntT1
            const double w = 1.0 / 128.0;        // bin width
            const double avg = sumT1 / (double)cntT1;
            // shifted-uniform top-Kp mean; exact when Kp == cntT1
            const double topmean = avg + 0.5 * w * (1.0 - (double)Kp / (double)cntT1);
            sum_sel = rsumgt + (double)Kp * topmean;
        }
    }

    if (tid == 0) {
        unsigned long long kk = (unsigned long long)npos + (unsigned long long)Kneg;
        double per_s = 0.0;
        if (kk > 0) per_s = (sumPos + sum_sel) / (double)kk;
        // kk==0 => no tissue => reference falls back to loss[:,0] == 0
        atomicAdd(out, (float)(per_s / (double)B_ROWS));
    }
}

// ---------- launch ----------
extern "C" void kernel_launch(void* const* d_in, const int* in_sizes, int n_in,
                              void* d_out, int out_size, void* d_ws, size_t ws_size,
                              hipStream_t stream)
{
    const float* logits = (const float*)d_in[0];
    const int*   targets = (const int*)d_in[1];
    const int*   tissue = (const int*)d_in[2];

    const int NBLK = B_ROWS * BLOCKS_PER_ROW;   // 1024
    char* ws = (char*)d_ws;
    size_t off = 0;
    // zeroed region: packed hist copies (at ws start)
    unsigned long long* hist = (unsigned long long*)(ws + off);
    off += (size_t)B_ROWS * NCOPY * NBINS * 8;   // 512 KB
    size_t zero_size = off;
    // non-zeroed partials (every slot written before read)
    unsigned* partNpos = (unsigned*)(ws + off); off += (size_t)NBLK * 4;
    double*   partSpos = (double*)(ws + off);   off += (size_t)NBLK * 8;

    hipMemsetAsync(ws, 0, zero_size, stream);

    k_pass1<<<NBLK, 256, 0, stream>>>(
        (const float4*)logits, (const int4*)targets, (const int4*)tissue,
        hist, partNpos, partSpos, (float*)d_out);
    k_final<<<B_ROWS, 256, 0, stream>>>(hist, partNpos, partSpos, (float*)d_out);
}